// Round 5
// baseline (436.028 us; speedup 1.0000x reference)
//
#include <hip/hip_runtime.h>

constexpr float ACCEL_SCALE = 0.01f;
constexpr float MAX_VEL = 0.1f;
constexpr float MAX_POS = 1.0f;

// ============================ PATH A (v5): two-level sort ============================
constexpr int GSHIFT = 11;            // 2048 nodes per group
constexpr int GSIZE  = 1 << GSHIFT;
constexpr int SCANW  = 128;           // requires NG+1 <= SCANW (and src < 128<<11)
constexpr int ANBLK  = 512;           // slices in pass 1
constexpr int RSPLIT = 4;             // resort/acc blocks per dst-group
constexpr int SPR    = ANBLK / RSPLIT;
constexpr int CSTEP  = 2;             // src-groups staged per acc step

// ---- pass 1: block-local sort by dst-group; packed1 = (src<<11)|local_dst ----
__global__ __launch_bounds__(256) void a_scatter_kernel(
    const int* __restrict__ src, const int* __restrict__ dst,
    int E, int NG, int chunk,
    unsigned* __restrict__ tab, unsigned* __restrict__ packed)
{
    __shared__ int cnt[SCANW];
    __shared__ int tmp[SCANW];
    __shared__ int cur[SCANW];
    int tid = threadIdx.x;
    long long cs64 = (long long)blockIdx.x * chunk;
    int cs = (cs64 > E) ? E : (int)cs64;
    int ce = min(cs + chunk, E);

    if (tid < SCANW) cnt[tid] = 0;
    __syncthreads();

    int nv = (ce - cs) >> 2;
    const int4* d4 = (const int4*)(dst + cs);
    for (int k = tid; k < nv; k += 256) {
        int4 v = d4[k];
        atomicAdd(&cnt[v.x >> GSHIFT], 1);
        atomicAdd(&cnt[v.y >> GSHIFT], 1);
        atomicAdd(&cnt[v.z >> GSHIFT], 1);
        atomicAdd(&cnt[v.w >> GSHIFT], 1);
    }
    for (int i = cs + (nv << 2) + tid; i < ce; i += 256)
        atomicAdd(&cnt[dst[i] >> GSHIFT], 1);
    __syncthreads();

    int v = (tid < SCANW) ? cnt[tid] : 0;
    if (tid < SCANW) tmp[tid] = v;
    __syncthreads();
    for (int off = 1; off < SCANW; off <<= 1) {
        int t = (tid < SCANW && tid >= off) ? tmp[tid - off] : 0;
        __syncthreads();
        if (tid < SCANW) tmp[tid] += t;
        __syncthreads();
    }
    if (tid < SCANW) {
        int base = tmp[tid] - v;
        cur[tid] = base;
        if (tid <= NG) tab[(size_t)blockIdx.x * (NG + 1) + tid] = (unsigned)base;
    }
    __syncthreads();

    const int4* s4 = (const int4*)(src + cs);
    for (int k = tid; k < nv; k += 256) {
        int4 dv = d4[k];
        int4 sv = s4[k];
        int p;
        p = atomicAdd(&cur[dv.x >> GSHIFT], 1);
        packed[cs + p] = ((unsigned)sv.x << GSHIFT) | (unsigned)(dv.x & (GSIZE - 1));
        p = atomicAdd(&cur[dv.y >> GSHIFT], 1);
        packed[cs + p] = ((unsigned)sv.y << GSHIFT) | (unsigned)(dv.y & (GSIZE - 1));
        p = atomicAdd(&cur[dv.z >> GSHIFT], 1);
        packed[cs + p] = ((unsigned)sv.z << GSHIFT) | (unsigned)(dv.z & (GSIZE - 1));
        p = atomicAdd(&cur[dv.w >> GSHIFT], 1);
        packed[cs + p] = ((unsigned)sv.w << GSHIFT) | (unsigned)(dv.w & (GSIZE - 1));
    }
    for (int i = cs + (nv << 2) + tid; i < ce; i += 256) {
        int dvv = dst[i], svv = src[i];
        int p = atomicAdd(&cur[dvv >> GSHIFT], 1);
        packed[cs + p] = ((unsigned)svv << GSHIFT) | (unsigned)(dvv & (GSIZE - 1));
    }
}

// ---- pass 2: per (dst-group g, quarter r): re-bin by src-group into packed2;
//      fused per-node degree count -> pdeg partials ----
__global__ __launch_bounds__(256) void a_resort_kernel(
    const unsigned* __restrict__ packed1, const unsigned* __restrict__ tab1,
    int E, int NG, int chunk, int n,
    unsigned* __restrict__ gctr, unsigned* __restrict__ tab2,
    unsigned* __restrict__ packed2, int* __restrict__ pdeg)
{
    __shared__ int hist[SCANW];
    __shared__ int tmp[SCANW];
    __shared__ int cur[SCANW];
    __shared__ int cnt[GSIZE];
    __shared__ unsigned sbase;
    int g = blockIdx.x / RSPLIT;
    int r = blockIdx.x - g * RSPLIT;
    int tid = threadIdx.x;
    if (tid < SCANW) hist[tid] = 0;
    for (int t = tid; t < GSIZE; t += 256) cnt[t] = 0;
    __syncthreads();

    int wave = tid >> 6, lane = tid & 63;
    int j0 = r * SPR, jend = j0 + SPR;

    // sweep 1: src-group histogram + per-node degree
    int j = j0 + wave;
    unsigned nt0 = 0, nt1 = 0;
    if (j < jend) { const unsigned* tr = tab1 + (size_t)j * (NG + 1) + g; nt0 = tr[0]; nt1 = tr[1]; }
    for (; j < jend; j += 4) {
        unsigned t0 = nt0, t1 = nt1;
        int jn = j + 4;
        if (jn < jend) { const unsigned* tr = tab1 + (size_t)jn * (NG + 1) + g; nt0 = tr[0]; nt1 = tr[1]; }
        long long cs64 = (long long)j * chunk;
        int cs = (cs64 > E) ? E : (int)cs64;
        for (unsigned i = t0 + lane; i < t1; i += 64) {
            unsigned p = packed1[cs + i];
            atomicAdd(&hist[p >> (2 * GSHIFT)], 1);
            atomicAdd(&cnt[p & (GSIZE - 1)], 1);
        }
    }
    __syncthreads();

    // scan + global base allocation
    int v = (tid < SCANW) ? hist[tid] : 0;
    if (tid < SCANW) tmp[tid] = v;
    __syncthreads();
    for (int off = 1; off < SCANW; off <<= 1) {
        int t = (tid < SCANW && tid >= off) ? tmp[tid - off] : 0;
        __syncthreads();
        if (tid < SCANW) tmp[tid] += t;
        __syncthreads();
    }
    if (tid == SCANW - 1) sbase = atomicAdd(gctr, (unsigned)tmp[SCANW - 1]);
    __syncthreads();
    if (tid < SCANW) {
        int excl = tmp[tid] - v;
        cur[tid] = (int)(sbase + (unsigned)excl);
        if (tid <= NG) tab2[(size_t)blockIdx.x * (NG + 1) + tid] = sbase + (unsigned)excl;
    }
    __syncthreads();

    // sweep 2: scatter into own contiguous range, src-group-sorted
    j = j0 + wave;
    if (j < jend) { const unsigned* tr = tab1 + (size_t)j * (NG + 1) + g; nt0 = tr[0]; nt1 = tr[1]; }
    for (; j < jend; j += 4) {
        unsigned t0 = nt0, t1 = nt1;
        int jn = j + 4;
        if (jn < jend) { const unsigned* tr = tab1 + (size_t)jn * (NG + 1) + g; nt0 = tr[0]; nt1 = tr[1]; }
        long long cs64 = (long long)j * chunk;
        int cs = (cs64 > E) ? E : (int)cs64;
        for (unsigned i = t0 + lane; i < t1; i += 64) {
            unsigned p = packed1[cs + i];
            int pos = atomicAdd(&cur[p >> (2 * GSHIFT)], 1);
            packed2[pos] = p;
        }
    }
    __syncthreads();

    size_t nb0 = (size_t)g << GSHIFT;
    for (int t = tid; t < GSIZE; t += 256) {
        size_t node = nb0 + t;
        if (node < (size_t)n) pdeg[(size_t)r * n + node] = cnt[t];
    }
}

// ---- fused: dinv = rsqrt(1 + sum pdeg), hs = (x @ W) * dinv ----
__global__ void node_pre_kernel(const float* __restrict__ x, const float* __restrict__ W,
                                const int* __restrict__ pdeg, int n, int nsplit,
                                float* __restrict__ dinv, float* __restrict__ hs) {
    int i = blockIdx.x * blockDim.x + threadIdx.x;
    if (i >= n) return;
    int d = 1;   // self loop
    for (int s = 0; s < nsplit; ++s) d += pdeg[(size_t)s * n + i];
    float di = rsqrtf((float)d);
    dinv[i] = di;
    const float* xr = x + (size_t)i * 5;
    float x0 = xr[0], x1 = xr[1], x2 = xr[2], x3 = xr[3], x4 = xr[4];
    float h0 = x0 * W[0] + x1 * W[2] + x2 * W[4] + x3 * W[6] + x4 * W[8];
    float h1 = x0 * W[1] + x1 * W[3] + x2 * W[5] + x3 * W[7] + x4 * W[9];
    hs[2 * i]     = h0 * di;
    hs[2 * i + 1] = h1 * di;
}

// ---- pass 3: per (g, r) block: stage hs per src-cluster in LDS, accumulate ----
__global__ __launch_bounds__(512) void a_acc2_kernel(
    const unsigned* __restrict__ packed2, const unsigned* __restrict__ tab2,
    const float* __restrict__ hs, int NG, int n,
    float2* __restrict__ ps)
{
    __shared__ float2 hstage[GSIZE * CSTEP];   // 32 KB
    __shared__ float accx[GSIZE];              // 8 KB
    __shared__ float accy[GSIZE];              // 8 KB
    int g = blockIdx.x / RSPLIT;
    int r = blockIdx.x - g * RSPLIT;
    int tid = threadIdx.x;
    for (int t = tid; t < GSIZE; t += 512) { accx[t] = 0.f; accy[t] = 0.f; }
    const unsigned* row = tab2 + (size_t)blockIdx.x * (NG + 1);
    const float2* h2 = (const float2*)hs;
    for (int c0 = 0; c0 < NG; c0 += CSTEP) {
        int cN = min(c0 + CSTEP, NG);
        __syncthreads();   // previous cluster's readers done (also covers acc init)
        int nstage = (cN - c0) << GSHIFT;
        unsigned gbase = (unsigned)c0 << GSHIFT;
        for (int t = tid; t < nstage; t += 512) {
            size_t node = (size_t)gbase + t;
            hstage[t] = (node < (size_t)n) ? h2[node] : make_float2(0.f, 0.f);
        }
        __syncthreads();
        unsigned s0 = row[c0], s1 = row[cN];
        for (unsigned i = s0 + tid; i < s1; i += 512) {
            unsigned p = packed2[i];
            float2 m = hstage[(p >> GSHIFT) - gbase];
            int ld = p & (GSIZE - 1);
            unsafeAtomicAdd(&accx[ld], m.x);
            unsafeAtomicAdd(&accy[ld], m.y);
        }
    }
    __syncthreads();
    size_t nb0 = (size_t)g << GSHIFT;
    for (int t = tid; t < GSIZE; t += 512) {
        size_t node = nb0 + t;
        if (node < (size_t)n) ps[(size_t)r * n + node] = make_float2(accx[t], accy[t]);
    }
}

__global__ void a_final_kernel(const float* __restrict__ x, const float2* __restrict__ ps,
                               const float* __restrict__ hs, const float* __restrict__ dinv,
                               const float* __restrict__ b, float* __restrict__ out,
                               int n, int nsplit) {
    int i = blockIdx.x * blockDim.x + threadIdx.x;
    if (i >= n) return;
    float sx = 0.f, sy = 0.f;
    for (int s = 0; s < nsplit; ++s) {
        float2 v = ps[(size_t)s * n + i];
        sx += v.x; sy += v.y;
    }
    const float2* h2 = (const float2*)hs;
    float di = dinv[i];
    float2 hv = h2[i];
    float c0 = di * (sx + hv.x) + b[0];
    float c1 = di * (sy + hv.y) + b[1];
    float a0 = c0 * ACCEL_SCALE;
    float a1 = c1 * ACCEL_SCALE;
    const float* xr = x + (size_t)i * 5;
    float v0 = fminf(fmaxf(xr[2] + a0, -MAX_VEL), MAX_VEL);
    float v1 = fminf(fmaxf(xr[3] + a1, -MAX_VEL), MAX_VEL);
    float p0 = fminf(fmaxf(xr[0] + v0, -MAX_POS), MAX_POS);
    float p1 = fminf(fmaxf(xr[1] + v1, -MAX_POS), MAX_POS);
    float* o = out + (size_t)i * 5;
    o[0] = p0; o[1] = p1; o[2] = v0; o[3] = v1; o[4] = xr[4];
}

// ============================ PATH F: round-4 fallback (segment-walk acc) ============================
__global__ __launch_bounds__(512) void f_deg_kernel(
    const unsigned* __restrict__ packed, const unsigned* __restrict__ tab,
    int E, int NG, int chunk, int n, int splitShift, int* __restrict__ pdeg)
{
    __shared__ int cnt[GSIZE];
    int g = blockIdx.x >> splitShift;
    int s = blockIdx.x & ((1 << splitShift) - 1);
    for (int t = threadIdx.x; t < GSIZE; t += 512) cnt[t] = 0;
    __syncthreads();
    int wave = threadIdx.x >> 6, lane = threadIdx.x & 63;
    int perSplit = ANBLK >> splitShift;
    int j0 = s * perSplit, jend = j0 + perSplit;
    int j = j0 + wave;
    unsigned nt0 = 0, nt1 = 0;
    if (j < jend) { const unsigned* tr = tab + (size_t)j * (NG + 1) + g; nt0 = tr[0]; nt1 = tr[1]; }
    for (; j < jend; j += 8) {
        unsigned t0 = nt0, t1 = nt1;
        int jn = j + 8;
        if (jn < jend) { const unsigned* tr = tab + (size_t)jn * (NG + 1) + g; nt0 = tr[0]; nt1 = tr[1]; }
        long long cs64 = (long long)j * chunk;
        int cs = (cs64 > E) ? E : (int)cs64;
        for (unsigned i = t0 + lane; i < t1; i += 64)
            atomicAdd(&cnt[packed[cs + i] & (GSIZE - 1)], 1);
    }
    __syncthreads();
    size_t nb0 = (size_t)g << GSHIFT;
    for (int t = threadIdx.x; t < GSIZE; t += 512) {
        size_t node = nb0 + t;
        if (node < (size_t)n) pdeg[(size_t)s * n + node] = cnt[t];
    }
}

__global__ __launch_bounds__(512) void f_acc_kernel(
    const unsigned* __restrict__ packed, const unsigned* __restrict__ tab,
    const float* __restrict__ hs, int E, int NG, int chunk, int n, int splitShift,
    float2* __restrict__ ps)
{
    __shared__ float accx[GSIZE];
    __shared__ float accy[GSIZE];
    int g = blockIdx.x >> splitShift;
    int s = blockIdx.x & ((1 << splitShift) - 1);
    for (int t = threadIdx.x; t < GSIZE; t += 512) { accx[t] = 0.f; accy[t] = 0.f; }
    __syncthreads();
    int wave = threadIdx.x >> 6, lane = threadIdx.x & 63;
    int perSplit = ANBLK >> splitShift;
    int j0 = s * perSplit, jend = j0 + perSplit;
    const float2* h2 = (const float2*)hs;
    int j = j0 + wave;
    unsigned nt0 = 0, nt1 = 0;
    if (j < jend) { const unsigned* tr = tab + (size_t)j * (NG + 1) + g; nt0 = tr[0]; nt1 = tr[1]; }
    for (; j < jend; j += 8) {
        unsigned t0 = nt0, t1 = nt1;
        int jn = j + 8;
        if (jn < jend) { const unsigned* tr = tab + (size_t)jn * (NG + 1) + g; nt0 = tr[0]; nt1 = tr[1]; }
        long long cs64 = (long long)j * chunk;
        int cs = (cs64 > E) ? E : (int)cs64;
        for (unsigned i = t0 + lane; i < t1; i += 64) {
            unsigned p = packed[cs + i];
            float2 m = h2[p >> GSHIFT];
            int ld = p & (GSIZE - 1);
            unsafeAtomicAdd(&accx[ld], m.x);
            unsafeAtomicAdd(&accy[ld], m.y);
        }
    }
    __syncthreads();
    size_t nb0 = (size_t)g << GSHIFT;
    for (int t = threadIdx.x; t < GSIZE; t += 512) {
        size_t node = nb0 + t;
        if (node < (size_t)n) ps[(size_t)s * n + node] = make_float2(accx[t], accy[t]);
    }
}

// ============================ PATH C: atomic fallback ============================
__global__ void fb_deg_kernel(const int* __restrict__ dst, int E, int* __restrict__ deg) {
    int tid = blockIdx.x * blockDim.x + threadIdx.x;
    int stride = gridDim.x * blockDim.x;
    for (int k = tid; k < E; k += stride) atomicAdd(&deg[dst[k]], 1);
}
__global__ void fb_scatter_kernel(const int* __restrict__ src, const int* __restrict__ dst,
                                  int E, const float* __restrict__ hs, float* __restrict__ s) {
    int tid = blockIdx.x * blockDim.x + threadIdx.x;
    int stride = gridDim.x * blockDim.x;
    const float2* h2 = (const float2*)hs;
    for (int k = tid; k < E; k += stride) {
        int sv = src[k], dv = dst[k];
        float2 m = h2[sv];
        unsafeAtomicAdd(&s[2 * dv], m.x);
        unsafeAtomicAdd(&s[2 * dv + 1], m.y);
    }
}
__global__ void fb_np_kernel(const float* __restrict__ x, const float* __restrict__ W,
                             const int* __restrict__ deg, int n,
                             float* __restrict__ dinv, float* __restrict__ hs) {
    int i = blockIdx.x * blockDim.x + threadIdx.x;
    if (i >= n) return;
    float di = rsqrtf((float)(deg[i] + 1));
    dinv[i] = di;
    const float* xr = x + (size_t)i * 5;
    float x0 = xr[0], x1 = xr[1], x2 = xr[2], x3 = xr[3], x4 = xr[4];
    float h0 = x0 * W[0] + x1 * W[2] + x2 * W[4] + x3 * W[6] + x4 * W[8];
    float h1 = x0 * W[1] + x1 * W[3] + x2 * W[5] + x3 * W[7] + x4 * W[9];
    hs[2 * i] = h0 * di;
    hs[2 * i + 1] = h1 * di;
}
__global__ void fb_finalize_kernel(const float* __restrict__ x, const float* __restrict__ s,
                                   const float* __restrict__ hs, const float* __restrict__ dinv,
                                   const float* __restrict__ b, float* __restrict__ out, int n) {
    int i = blockIdx.x * blockDim.x + threadIdx.x;
    if (i >= n) return;
    float di = dinv[i];
    const float2* s2 = (const float2*)s;
    const float2* h2 = (const float2*)hs;
    float2 sv = s2[i];
    float2 hv = h2[i];
    float c0 = di * (sv.x + hv.x) + b[0];
    float c1 = di * (sv.y + hv.y) + b[1];
    float a0 = c0 * ACCEL_SCALE, a1 = c1 * ACCEL_SCALE;
    const float* xr = x + (size_t)i * 5;
    float v0 = fminf(fmaxf(xr[2] + a0, -MAX_VEL), MAX_VEL);
    float v1 = fminf(fmaxf(xr[3] + a1, -MAX_VEL), MAX_VEL);
    float p0 = fminf(fmaxf(xr[0] + v0, -MAX_POS), MAX_POS);
    float p1 = fminf(fmaxf(xr[1] + v1, -MAX_POS), MAX_POS);
    float* o = out + (size_t)i * 5;
    o[0] = p0; o[1] = p1; o[2] = v0; o[3] = v1; o[4] = xr[4];
}

extern "C" void kernel_launch(void* const* d_in, const int* in_sizes, int n_in,
                              void* d_out, int out_size, void* d_ws, size_t ws_size,
                              hipStream_t stream) {
    const float* x    = (const float*)d_in[0];
    const int*   edge = (const int*)d_in[1];
    const float* W    = (const float*)d_in[2];
    const float* b    = (const float*)d_in[3];

    int n = in_sizes[0] / 5;
    int E = in_sizes[1] / 2;
    const int* src = edge;
    const int* dst = edge + E;

    const int BLK = 256;
    int node_blocks = (n + BLK - 1) / BLK;
    int NG = (n + GSIZE - 1) >> GSHIFT;
    int chunk = ((E + ANBLK - 1) / ANBLK + 3) & ~3;
    bool geomOK = (NG >= 1) && (NG + 1 <= SCANW) && (E >= 8);

    // ---------- path A (v5): scatter -> resort(+deg) -> node_pre -> staged acc ----------
    if (geomOK) {
        size_t wTab1 = (size_t)ANBLK * (NG + 1);
        size_t wTab2 = (size_t)NG * RSPLIT * (NG + 1);
        size_t needW = 4 + 2 * (size_t)E + wTab1 + wTab2
                     + (size_t)RSPLIT * n + (size_t)n + 2 * (size_t)n;
        bool overlayOK = (size_t)E >= (size_t)RSPLIT * n * 2;   // ps fits over packed1
        if (ws_size >= needW * 4 && overlayOK) {
            unsigned* gctr    = (unsigned*)d_ws;
            unsigned* packed2 = gctr + 4;
            unsigned* packed1 = packed2 + E;
            unsigned* tab1    = packed1 + E;
            unsigned* tab2    = tab1 + wTab1;
            int*      pdeg    = (int*)(tab2 + wTab2);
            float*    dinv    = (float*)(pdeg + (size_t)RSPLIT * n);
            float*    hs      = dinv + n;
            float2*   ps      = (float2*)packed1;   // overlay: packed1 dead after resort

            hipMemsetAsync(gctr, 0, sizeof(unsigned), stream);
            a_scatter_kernel<<<ANBLK, 256, 0, stream>>>(src, dst, E, NG, chunk, tab1, packed1);
            a_resort_kernel<<<NG * RSPLIT, 256, 0, stream>>>(packed1, tab1, E, NG, chunk, n,
                                                             gctr, tab2, packed2, pdeg);
            node_pre_kernel<<<node_blocks, BLK, 0, stream>>>(x, W, pdeg, n, RSPLIT, dinv, hs);
            a_acc2_kernel<<<NG * RSPLIT, 512, 0, stream>>>(packed2, tab2, hs, NG, n, ps);
            a_final_kernel<<<node_blocks, BLK, 0, stream>>>(x, ps, hs, dinv, b,
                                                            (float*)d_out, n, RSPLIT);
            return;
        }
    }

    // ---------- path F: round-4 pipeline (single sort, direct-gather acc) ----------
    if (geomOK) {
        size_t baseW = (size_t)E + (size_t)ANBLK * (NG + 1) + (size_t)n + 2 * (size_t)n;
        size_t needF = (baseW + (size_t)4 * n * 2) * 4;   // split 4 partials (float2)
        if (ws_size >= needF) {
            const int splitShift = 2, split = 4;
            unsigned* packed = (unsigned*)d_ws;
            unsigned* tab    = packed + E;
            int* region      = (int*)(tab + (size_t)ANBLK * (NG + 1));
            int* pdeg        = region;
            float2* ps       = (float2*)region;
            float* dinv      = (float*)(region + (size_t)split * n * 2);
            float* hs        = dinv + n;

            a_scatter_kernel<<<ANBLK, 256, 0, stream>>>(src, dst, E, NG, chunk, tab, packed);
            f_deg_kernel<<<NG << splitShift, 512, 0, stream>>>(packed, tab, E, NG, chunk, n,
                                                               splitShift, pdeg);
            node_pre_kernel<<<node_blocks, BLK, 0, stream>>>(x, W, pdeg, n, split, dinv, hs);
            f_acc_kernel<<<NG << splitShift, 512, 0, stream>>>(packed, tab, hs, E, NG, chunk, n,
                                                               splitShift, ps);
            a_final_kernel<<<node_blocks, BLK, 0, stream>>>(x, ps, hs, dinv, b,
                                                            (float*)d_out, n, split);
            return;
        }
    }

    // ---------- path C: atomic fallback ----------
    {
        float* dinv = (float*)d_ws;
        float* hs   = dinv + n;
        float* s    = hs + 2 * (size_t)n;
        int*   deg  = (int*)(s + 2 * (size_t)n);
        hipMemsetAsync(deg, 0, (size_t)n * sizeof(int), stream);
        hipMemsetAsync(s,   0, (size_t)n * 2 * sizeof(float), stream);
        fb_deg_kernel<<<4096, BLK, 0, stream>>>(dst, E, deg);
        fb_np_kernel<<<node_blocks, BLK, 0, stream>>>(x, W, deg, n, dinv, hs);
        fb_scatter_kernel<<<4096, BLK, 0, stream>>>(src, dst, E, hs, s);
        fb_finalize_kernel<<<node_blocks, BLK, 0, stream>>>(x, s, hs, dinv, b, (float*)d_out, n);
    }
}

// Round 6
// 367.826 us; speedup vs baseline: 1.1854x; 1.1854x over previous
//
#include <hip/hip_runtime.h>
#include <hip/hip_fp16.h>

constexpr float ACCEL_SCALE = 0.01f;
constexpr float MAX_VEL = 0.1f;
constexpr float MAX_POS = 1.0f;

constexpr int GSHIFT = 11;            // 2048 nodes per group
constexpr int GSIZE  = 1 << GSHIFT;
constexpr int SCANW  = 128;           // requires NG+1 <= SCANW
constexpr int ANBLK  = 512;           // slices in pass 1
constexpr int RSPLIT = 2;             // resort/acc blocks per dst-group
constexpr int SPR    = ANBLK / RSPLIT;

// ---- pass 1: block-local sort by dst-group; packed1 = (src<<11)|local_dst ----
__global__ __launch_bounds__(256) void a_scatter_kernel(
    const int* __restrict__ src, const int* __restrict__ dst,
    int E, int NG, int chunk,
    unsigned* __restrict__ tab, unsigned* __restrict__ packed)
{
    __shared__ int cnt[SCANW];
    __shared__ int tmp[SCANW];
    __shared__ int cur[SCANW];
    int tid = threadIdx.x;
    long long cs64 = (long long)blockIdx.x * chunk;
    int cs = (cs64 > E) ? E : (int)cs64;
    int ce = min(cs + chunk, E);

    if (tid < SCANW) cnt[tid] = 0;
    __syncthreads();

    int nv = (ce - cs) >> 2;
    const int4* d4 = (const int4*)(dst + cs);
    for (int k = tid; k < nv; k += 256) {
        int4 v = d4[k];
        atomicAdd(&cnt[v.x >> GSHIFT], 1);
        atomicAdd(&cnt[v.y >> GSHIFT], 1);
        atomicAdd(&cnt[v.z >> GSHIFT], 1);
        atomicAdd(&cnt[v.w >> GSHIFT], 1);
    }
    for (int i = cs + (nv << 2) + tid; i < ce; i += 256)
        atomicAdd(&cnt[dst[i] >> GSHIFT], 1);
    __syncthreads();

    int v = (tid < SCANW) ? cnt[tid] : 0;
    if (tid < SCANW) tmp[tid] = v;
    __syncthreads();
    for (int off = 1; off < SCANW; off <<= 1) {
        int t = (tid < SCANW && tid >= off) ? tmp[tid - off] : 0;
        __syncthreads();
        if (tid < SCANW) tmp[tid] += t;
        __syncthreads();
    }
    if (tid < SCANW) {
        int base = tmp[tid] - v;
        cur[tid] = base;
        if (tid <= NG) tab[(size_t)blockIdx.x * (NG + 1) + tid] = (unsigned)base;
    }
    __syncthreads();

    const int4* s4 = (const int4*)(src + cs);
    for (int k = tid; k < nv; k += 256) {
        int4 dv = d4[k];
        int4 sv = s4[k];
        int p;
        p = atomicAdd(&cur[dv.x >> GSHIFT], 1);
        packed[cs + p] = ((unsigned)sv.x << GSHIFT) | (unsigned)(dv.x & (GSIZE - 1));
        p = atomicAdd(&cur[dv.y >> GSHIFT], 1);
        packed[cs + p] = ((unsigned)sv.y << GSHIFT) | (unsigned)(dv.y & (GSIZE - 1));
        p = atomicAdd(&cur[dv.z >> GSHIFT], 1);
        packed[cs + p] = ((unsigned)sv.z << GSHIFT) | (unsigned)(dv.z & (GSIZE - 1));
        p = atomicAdd(&cur[dv.w >> GSHIFT], 1);
        packed[cs + p] = ((unsigned)sv.w << GSHIFT) | (unsigned)(dv.w & (GSIZE - 1));
    }
    for (int i = cs + (nv << 2) + tid; i < ce; i += 256) {
        int dvv = dst[i], svv = src[i];
        int p = atomicAdd(&cur[dvv >> GSHIFT], 1);
        packed[cs + p] = ((unsigned)svv << GSHIFT) | (unsigned)(dvv & (GSIZE - 1));
    }
}

// ---- pass 2: per (dst-group g, half r): re-bin by src-group into packed2;
//      fused per-node degree count -> pdeg partials ----
__global__ __launch_bounds__(512) void a_resort_kernel(
    const unsigned* __restrict__ packed1, const unsigned* __restrict__ tab1,
    int E, int NG, int chunk, int n,
    unsigned* __restrict__ gctr, unsigned* __restrict__ tab2,
    unsigned* __restrict__ packed2, int* __restrict__ pdeg)
{
    __shared__ int hist[SCANW];
    __shared__ int tmp[SCANW];
    __shared__ int cur[SCANW];
    __shared__ int cnt[GSIZE];
    __shared__ unsigned sbase;
    int g = blockIdx.x / RSPLIT;
    int r = blockIdx.x - g * RSPLIT;
    int tid = threadIdx.x;
    if (tid < SCANW) hist[tid] = 0;
    for (int t = tid; t < GSIZE; t += 512) cnt[t] = 0;
    __syncthreads();

    int wave = tid >> 6, lane = tid & 63;
    int j0 = r * SPR, jend = j0 + SPR;

    // sweep 1: src-group histogram + per-node degree
    int j = j0 + wave;
    unsigned nt0 = 0, nt1 = 0;
    if (j < jend) { const unsigned* tr = tab1 + (size_t)j * (NG + 1) + g; nt0 = tr[0]; nt1 = tr[1]; }
    for (; j < jend; j += 8) {
        unsigned t0 = nt0, t1 = nt1;
        int jn = j + 8;
        if (jn < jend) { const unsigned* tr = tab1 + (size_t)jn * (NG + 1) + g; nt0 = tr[0]; nt1 = tr[1]; }
        long long cs64 = (long long)j * chunk;
        int cs = (cs64 > E) ? E : (int)cs64;
        for (unsigned i = t0 + lane; i < t1; i += 64) {
            unsigned p = packed1[cs + i];
            atomicAdd(&hist[p >> (2 * GSHIFT)], 1);
            atomicAdd(&cnt[p & (GSIZE - 1)], 1);
        }
    }
    __syncthreads();

    // scan + global base allocation
    int v = (tid < SCANW) ? hist[tid] : 0;
    if (tid < SCANW) tmp[tid] = v;
    __syncthreads();
    for (int off = 1; off < SCANW; off <<= 1) {
        int t = (tid < SCANW && tid >= off) ? tmp[tid - off] : 0;
        __syncthreads();
        if (tid < SCANW) tmp[tid] += t;
        __syncthreads();
    }
    if (tid == SCANW - 1) sbase = atomicAdd(gctr, (unsigned)tmp[SCANW - 1]);
    __syncthreads();
    if (tid < SCANW) {
        int excl = tmp[tid] - v;
        cur[tid] = (int)(sbase + (unsigned)excl);
        if (tid <= NG) tab2[(size_t)blockIdx.x * (NG + 1) + tid] = sbase + (unsigned)excl;
    }
    __syncthreads();

    // sweep 2: scatter into own contiguous range, src-group-sorted
    j = j0 + wave;
    if (j < jend) { const unsigned* tr = tab1 + (size_t)j * (NG + 1) + g; nt0 = tr[0]; nt1 = tr[1]; }
    for (; j < jend; j += 8) {
        unsigned t0 = nt0, t1 = nt1;
        int jn = j + 8;
        if (jn < jend) { const unsigned* tr = tab1 + (size_t)jn * (NG + 1) + g; nt0 = tr[0]; nt1 = tr[1]; }
        long long cs64 = (long long)j * chunk;
        int cs = (cs64 > E) ? E : (int)cs64;
        for (unsigned i = t0 + lane; i < t1; i += 64) {
            unsigned p = packed1[cs + i];
            int pos = atomicAdd(&cur[p >> (2 * GSHIFT)], 1);
            packed2[pos] = p;
        }
    }
    __syncthreads();

    size_t nb0 = (size_t)g << GSHIFT;
    for (int t = tid; t < GSIZE; t += 512) {
        size_t node = nb0 + t;
        if (node < (size_t)n) pdeg[(size_t)r * n + node] = cnt[t];
    }
}

// ---- fused: dinv = rsqrt(1 + sum pdeg); hsh = half2((x@W) * dinv) ----
__global__ void node_preh_kernel(const float* __restrict__ x, const float* __restrict__ W,
                                 const int* __restrict__ pdeg, int n, int nsplit,
                                 float* __restrict__ dinv, __half2* __restrict__ hsh) {
    int i = blockIdx.x * blockDim.x + threadIdx.x;
    if (i >= n) return;
    int d = 1;   // self loop
    for (int s = 0; s < nsplit; ++s) d += pdeg[(size_t)s * n + i];
    float di = rsqrtf((float)d);
    dinv[i] = di;
    const float* xr = x + (size_t)i * 5;
    float x0 = xr[0], x1 = xr[1], x2 = xr[2], x3 = xr[3], x4 = xr[4];
    float h0 = x0 * W[0] + x1 * W[2] + x2 * W[4] + x3 * W[6] + x4 * W[8];
    float h1 = x0 * W[1] + x1 * W[3] + x2 * W[5] + x3 * W[7] + x4 * W[9];
    hsh[i] = __floats2half2_rn(h0 * di, h1 * di);
}

// ---- pass 3: per (g,r) block: barrier-free march over src-sorted segment ----
__global__ __launch_bounds__(1024) void a_acc3_kernel(
    const unsigned* __restrict__ packed2, const unsigned* __restrict__ tab2,
    const __half2* __restrict__ hsh, int NG, int n,
    float2* __restrict__ ps)
{
    __shared__ float accx[GSIZE];
    __shared__ float accy[GSIZE];
    int g = blockIdx.x / RSPLIT;
    int r = blockIdx.x - g * RSPLIT;
    int tid = threadIdx.x;
    for (int t = tid; t < GSIZE; t += 1024) { accx[t] = 0.f; accy[t] = 0.f; }
    __syncthreads();
    const unsigned* row = tab2 + (size_t)blockIdx.x * (NG + 1);
    unsigned s0 = row[0], s1 = row[NG];
    unsigned i = s0 + tid;
    // 4-way unrolled march: 4 outstanding gathers per thread
    for (; i + 3072 < s1; i += 4096) {
        unsigned p0 = packed2[i];
        unsigned p1 = packed2[i + 1024];
        unsigned p2 = packed2[i + 2048];
        unsigned p3 = packed2[i + 3072];
        float2 m0 = __half22float2(hsh[p0 >> GSHIFT]);
        float2 m1 = __half22float2(hsh[p1 >> GSHIFT]);
        float2 m2 = __half22float2(hsh[p2 >> GSHIFT]);
        float2 m3 = __half22float2(hsh[p3 >> GSHIFT]);
        unsafeAtomicAdd(&accx[p0 & (GSIZE - 1)], m0.x);
        unsafeAtomicAdd(&accy[p0 & (GSIZE - 1)], m0.y);
        unsafeAtomicAdd(&accx[p1 & (GSIZE - 1)], m1.x);
        unsafeAtomicAdd(&accy[p1 & (GSIZE - 1)], m1.y);
        unsafeAtomicAdd(&accx[p2 & (GSIZE - 1)], m2.x);
        unsafeAtomicAdd(&accy[p2 & (GSIZE - 1)], m2.y);
        unsafeAtomicAdd(&accx[p3 & (GSIZE - 1)], m3.x);
        unsafeAtomicAdd(&accy[p3 & (GSIZE - 1)], m3.y);
    }
    for (; i < s1; i += 1024) {
        unsigned p = packed2[i];
        float2 m = __half22float2(hsh[p >> GSHIFT]);
        unsafeAtomicAdd(&accx[p & (GSIZE - 1)], m.x);
        unsafeAtomicAdd(&accy[p & (GSIZE - 1)], m.y);
    }
    __syncthreads();
    size_t nb0 = (size_t)g << GSHIFT;
    for (int t = tid; t < GSIZE; t += 1024) {
        size_t node = nb0 + t;
        if (node < (size_t)n) ps[(size_t)r * n + node] = make_float2(accx[t], accy[t]);
    }
}

// ---- final: sum partials, recompute self term, integrate + clip ----
__global__ void a_finalh_kernel(const float* __restrict__ x, const float2* __restrict__ ps,
                                const float* __restrict__ W, const float* __restrict__ dinv,
                                const float* __restrict__ b, float* __restrict__ out,
                                int n, int nsplit) {
    int i = blockIdx.x * blockDim.x + threadIdx.x;
    if (i >= n) return;
    float sx = 0.f, sy = 0.f;
    for (int s = 0; s < nsplit; ++s) {
        float2 v = ps[(size_t)s * n + i];
        sx += v.x; sy += v.y;
    }
    float di = dinv[i];
    const float* xr = x + (size_t)i * 5;
    float x0 = xr[0], x1 = xr[1], x2 = xr[2], x3 = xr[3], x4 = xr[4];
    float h0 = x0 * W[0] + x1 * W[2] + x2 * W[4] + x3 * W[6] + x4 * W[8];
    float h1 = x0 * W[1] + x1 * W[3] + x2 * W[5] + x3 * W[7] + x4 * W[9];
    float c0 = di * (sx + h0 * di) + b[0];
    float c1 = di * (sy + h1 * di) + b[1];
    float a0 = c0 * ACCEL_SCALE;
    float a1 = c1 * ACCEL_SCALE;
    float v0 = fminf(fmaxf(x2 + a0, -MAX_VEL), MAX_VEL);
    float v1 = fminf(fmaxf(x3 + a1, -MAX_VEL), MAX_VEL);
    float p0 = fminf(fmaxf(x0 + v0, -MAX_POS), MAX_POS);
    float p1 = fminf(fmaxf(x1 + v1, -MAX_POS), MAX_POS);
    float* o = out + (size_t)i * 5;
    o[0] = p0; o[1] = p1; o[2] = v0; o[3] = v1; o[4] = x4;
}

// ============================ PATH F: round-4 fallback ============================
__global__ void node_pre_kernel(const float* __restrict__ x, const float* __restrict__ W,
                                const int* __restrict__ pdeg, int n, int nsplit,
                                float* __restrict__ dinv, float* __restrict__ hs) {
    int i = blockIdx.x * blockDim.x + threadIdx.x;
    if (i >= n) return;
    int d = 1;
    for (int s = 0; s < nsplit; ++s) d += pdeg[(size_t)s * n + i];
    float di = rsqrtf((float)d);
    dinv[i] = di;
    const float* xr = x + (size_t)i * 5;
    float x0 = xr[0], x1 = xr[1], x2 = xr[2], x3 = xr[3], x4 = xr[4];
    float h0 = x0 * W[0] + x1 * W[2] + x2 * W[4] + x3 * W[6] + x4 * W[8];
    float h1 = x0 * W[1] + x1 * W[3] + x2 * W[5] + x3 * W[7] + x4 * W[9];
    hs[2 * i]     = h0 * di;
    hs[2 * i + 1] = h1 * di;
}

__global__ __launch_bounds__(512) void f_deg_kernel(
    const unsigned* __restrict__ packed, const unsigned* __restrict__ tab,
    int E, int NG, int chunk, int n, int splitShift, int* __restrict__ pdeg)
{
    __shared__ int cnt[GSIZE];
    int g = blockIdx.x >> splitShift;
    int s = blockIdx.x & ((1 << splitShift) - 1);
    for (int t = threadIdx.x; t < GSIZE; t += 512) cnt[t] = 0;
    __syncthreads();
    int wave = threadIdx.x >> 6, lane = threadIdx.x & 63;
    int perSplit = ANBLK >> splitShift;
    int j0 = s * perSplit, jend = j0 + perSplit;
    int j = j0 + wave;
    unsigned nt0 = 0, nt1 = 0;
    if (j < jend) { const unsigned* tr = tab + (size_t)j * (NG + 1) + g; nt0 = tr[0]; nt1 = tr[1]; }
    for (; j < jend; j += 8) {
        unsigned t0 = nt0, t1 = nt1;
        int jn = j + 8;
        if (jn < jend) { const unsigned* tr = tab + (size_t)jn * (NG + 1) + g; nt0 = tr[0]; nt1 = tr[1]; }
        long long cs64 = (long long)j * chunk;
        int cs = (cs64 > E) ? E : (int)cs64;
        for (unsigned i = t0 + lane; i < t1; i += 64)
            atomicAdd(&cnt[packed[cs + i] & (GSIZE - 1)], 1);
    }
    __syncthreads();
    size_t nb0 = (size_t)g << GSHIFT;
    for (int t = threadIdx.x; t < GSIZE; t += 512) {
        size_t node = nb0 + t;
        if (node < (size_t)n) pdeg[(size_t)s * n + node] = cnt[t];
    }
}

__global__ __launch_bounds__(512) void f_acc_kernel(
    const unsigned* __restrict__ packed, const unsigned* __restrict__ tab,
    const float* __restrict__ hs, int E, int NG, int chunk, int n, int splitShift,
    float2* __restrict__ ps)
{
    __shared__ float accx[GSIZE];
    __shared__ float accy[GSIZE];
    int g = blockIdx.x >> splitShift;
    int s = blockIdx.x & ((1 << splitShift) - 1);
    for (int t = threadIdx.x; t < GSIZE; t += 512) { accx[t] = 0.f; accy[t] = 0.f; }
    __syncthreads();
    int wave = threadIdx.x >> 6, lane = threadIdx.x & 63;
    int perSplit = ANBLK >> splitShift;
    int j0 = s * perSplit, jend = j0 + perSplit;
    const float2* h2 = (const float2*)hs;
    int j = j0 + wave;
    unsigned nt0 = 0, nt1 = 0;
    if (j < jend) { const unsigned* tr = tab + (size_t)j * (NG + 1) + g; nt0 = tr[0]; nt1 = tr[1]; }
    for (; j < jend; j += 8) {
        unsigned t0 = nt0, t1 = nt1;
        int jn = j + 8;
        if (jn < jend) { const unsigned* tr = tab + (size_t)jn * (NG + 1) + g; nt0 = tr[0]; nt1 = tr[1]; }
        long long cs64 = (long long)j * chunk;
        int cs = (cs64 > E) ? E : (int)cs64;
        for (unsigned i = t0 + lane; i < t1; i += 64) {
            unsigned p = packed[cs + i];
            float2 m = h2[p >> GSHIFT];
            int ld = p & (GSIZE - 1);
            unsafeAtomicAdd(&accx[ld], m.x);
            unsafeAtomicAdd(&accy[ld], m.y);
        }
    }
    __syncthreads();
    size_t nb0 = (size_t)g << GSHIFT;
    for (int t = threadIdx.x; t < GSIZE; t += 512) {
        size_t node = nb0 + t;
        if (node < (size_t)n) ps[(size_t)s * n + node] = make_float2(accx[t], accy[t]);
    }
}

__global__ void a_final_kernel(const float* __restrict__ x, const float2* __restrict__ ps,
                               const float* __restrict__ hs, const float* __restrict__ dinv,
                               const float* __restrict__ b, float* __restrict__ out,
                               int n, int nsplit) {
    int i = blockIdx.x * blockDim.x + threadIdx.x;
    if (i >= n) return;
    float sx = 0.f, sy = 0.f;
    for (int s = 0; s < nsplit; ++s) {
        float2 v = ps[(size_t)s * n + i];
        sx += v.x; sy += v.y;
    }
    const float2* h2 = (const float2*)hs;
    float di = dinv[i];
    float2 hv = h2[i];
    float c0 = di * (sx + hv.x) + b[0];
    float c1 = di * (sy + hv.y) + b[1];
    float a0 = c0 * ACCEL_SCALE;
    float a1 = c1 * ACCEL_SCALE;
    const float* xr = x + (size_t)i * 5;
    float v0 = fminf(fmaxf(xr[2] + a0, -MAX_VEL), MAX_VEL);
    float v1 = fminf(fmaxf(xr[3] + a1, -MAX_VEL), MAX_VEL);
    float p0 = fminf(fmaxf(xr[0] + v0, -MAX_POS), MAX_POS);
    float p1 = fminf(fmaxf(xr[1] + v1, -MAX_POS), MAX_POS);
    float* o = out + (size_t)i * 5;
    o[0] = p0; o[1] = p1; o[2] = v0; o[3] = v1; o[4] = xr[4];
}

// ============================ PATH C: atomic fallback ============================
__global__ void fb_deg_kernel(const int* __restrict__ dst, int E, int* __restrict__ deg) {
    int tid = blockIdx.x * blockDim.x + threadIdx.x;
    int stride = gridDim.x * blockDim.x;
    for (int k = tid; k < E; k += stride) atomicAdd(&deg[dst[k]], 1);
}
__global__ void fb_scatter_kernel(const int* __restrict__ src, const int* __restrict__ dst,
                                  int E, const float* __restrict__ hs, float* __restrict__ s) {
    int tid = blockIdx.x * blockDim.x + threadIdx.x;
    int stride = gridDim.x * blockDim.x;
    const float2* h2 = (const float2*)hs;
    for (int k = tid; k < E; k += stride) {
        int sv = src[k], dv = dst[k];
        float2 m = h2[sv];
        unsafeAtomicAdd(&s[2 * dv], m.x);
        unsafeAtomicAdd(&s[2 * dv + 1], m.y);
    }
}
__global__ void fb_np_kernel(const float* __restrict__ x, const float* __restrict__ W,
                             const int* __restrict__ deg, int n,
                             float* __restrict__ dinv, float* __restrict__ hs) {
    int i = blockIdx.x * blockDim.x + threadIdx.x;
    if (i >= n) return;
    float di = rsqrtf((float)(deg[i] + 1));
    dinv[i] = di;
    const float* xr = x + (size_t)i * 5;
    float x0 = xr[0], x1 = xr[1], x2 = xr[2], x3 = xr[3], x4 = xr[4];
    float h0 = x0 * W[0] + x1 * W[2] + x2 * W[4] + x3 * W[6] + x4 * W[8];
    float h1 = x0 * W[1] + x1 * W[3] + x2 * W[5] + x3 * W[7] + x4 * W[9];
    hs[2 * i] = h0 * di;
    hs[2 * i + 1] = h1 * di;
}
__global__ void fb_finalize_kernel(const float* __restrict__ x, const float* __restrict__ s,
                                   const float* __restrict__ hs, const float* __restrict__ dinv,
                                   const float* __restrict__ b, float* __restrict__ out, int n) {
    int i = blockIdx.x * blockDim.x + threadIdx.x;
    if (i >= n) return;
    float di = dinv[i];
    const float2* s2 = (const float2*)s;
    const float2* h2 = (const float2*)hs;
    float2 sv = s2[i];
    float2 hv = h2[i];
    float c0 = di * (sv.x + hv.x) + b[0];
    float c1 = di * (sv.y + hv.y) + b[1];
    float a0 = c0 * ACCEL_SCALE, a1 = c1 * ACCEL_SCALE;
    const float* xr = x + (size_t)i * 5;
    float v0 = fminf(fmaxf(xr[2] + a0, -MAX_VEL), MAX_VEL);
    float v1 = fminf(fmaxf(xr[3] + a1, -MAX_VEL), MAX_VEL);
    float p0 = fminf(fmaxf(xr[0] + v0, -MAX_POS), MAX_POS);
    float p1 = fminf(fmaxf(xr[1] + v1, -MAX_POS), MAX_POS);
    float* o = out + (size_t)i * 5;
    o[0] = p0; o[1] = p1; o[2] = v0; o[3] = v1; o[4] = xr[4];
}

extern "C" void kernel_launch(void* const* d_in, const int* in_sizes, int n_in,
                              void* d_out, int out_size, void* d_ws, size_t ws_size,
                              hipStream_t stream) {
    const float* x    = (const float*)d_in[0];
    const int*   edge = (const int*)d_in[1];
    const float* W    = (const float*)d_in[2];
    const float* b    = (const float*)d_in[3];

    int n = in_sizes[0] / 5;
    int E = in_sizes[1] / 2;
    const int* src = edge;
    const int* dst = edge + E;

    const int BLK = 256;
    int node_blocks = (n + BLK - 1) / BLK;
    int NG = (n + GSIZE - 1) >> GSHIFT;
    int chunk = ((E + ANBLK - 1) / ANBLK + 3) & ~3;
    bool geomOK = (NG >= 1) && (NG + 1 <= SCANW) && (n <= (1 << 21)) && (E >= 8);

    // ---------- path A (v6): scatter -> resort(+deg) -> node_pre(half2) -> march acc ----------
    if (geomOK) {
        size_t wTab1 = (size_t)ANBLK * (NG + 1);
        size_t wTab2 = (size_t)NG * RSPLIT * (NG + 1);
        size_t needW = 4 + 2 * (size_t)E + wTab1 + wTab2
                     + (size_t)RSPLIT * n + (size_t)n + (size_t)n;   // pdeg + dinv + hsh
        bool overlayOK = (size_t)E >= (size_t)RSPLIT * n * 2;        // ps fits over packed1
        if (ws_size >= needW * 4 && overlayOK) {
            unsigned* gctr    = (unsigned*)d_ws;
            unsigned* packed2 = gctr + 4;
            unsigned* packed1 = packed2 + E;
            unsigned* tab1    = packed1 + E;
            unsigned* tab2    = tab1 + wTab1;
            int*      pdeg    = (int*)(tab2 + wTab2);
            float*    dinv    = (float*)(pdeg + (size_t)RSPLIT * n);
            __half2*  hsh     = (__half2*)(dinv + n);
            float2*   ps      = (float2*)packed1;   // overlay: packed1 dead after resort

            hipMemsetAsync(gctr, 0, sizeof(unsigned), stream);
            a_scatter_kernel<<<ANBLK, 256, 0, stream>>>(src, dst, E, NG, chunk, tab1, packed1);
            a_resort_kernel<<<NG * RSPLIT, 512, 0, stream>>>(packed1, tab1, E, NG, chunk, n,
                                                             gctr, tab2, packed2, pdeg);
            node_preh_kernel<<<node_blocks, BLK, 0, stream>>>(x, W, pdeg, n, RSPLIT, dinv, hsh);
            a_acc3_kernel<<<NG * RSPLIT, 1024, 0, stream>>>(packed2, tab2, hsh, NG, n, ps);
            a_finalh_kernel<<<node_blocks, BLK, 0, stream>>>(x, ps, W, dinv, b,
                                                             (float*)d_out, n, RSPLIT);
            return;
        }
    }

    // ---------- path F: round-4 pipeline (single sort, direct-gather acc) ----------
    if (geomOK) {
        size_t baseW = (size_t)E + (size_t)ANBLK * (NG + 1) + (size_t)n + 2 * (size_t)n;
        size_t needF = (baseW + (size_t)4 * n * 2) * 4;
        if (ws_size >= needF) {
            const int splitShift = 2, split = 4;
            unsigned* packed = (unsigned*)d_ws;
            unsigned* tab    = packed + E;
            int* region      = (int*)(tab + (size_t)ANBLK * (NG + 1));
            int* pdeg        = region;
            float2* ps       = (float2*)region;
            float* dinv      = (float*)(region + (size_t)split * n * 2);
            float* hs        = dinv + n;

            a_scatter_kernel<<<ANBLK, 256, 0, stream>>>(src, dst, E, NG, chunk, tab, packed);
            f_deg_kernel<<<NG << splitShift, 512, 0, stream>>>(packed, tab, E, NG, chunk, n,
                                                               splitShift, pdeg);
            node_pre_kernel<<<node_blocks, BLK, 0, stream>>>(x, W, pdeg, n, split, dinv, hs);
            f_acc_kernel<<<NG << splitShift, 512, 0, stream>>>(packed, tab, hs, E, NG, chunk, n,
                                                               splitShift, ps);
            a_final_kernel<<<node_blocks, BLK, 0, stream>>>(x, ps, hs, dinv, b,
                                                            (float*)d_out, n, split);
            return;
        }
    }

    // ---------- path C: atomic fallback ----------
    {
        float* dinv = (float*)d_ws;
        float* hs   = dinv + n;
        float* s    = hs + 2 * (size_t)n;
        int*   deg  = (int*)(s + 2 * (size_t)n);
        hipMemsetAsync(deg, 0, (size_t)n * sizeof(int), stream);
        hipMemsetAsync(s,   0, (size_t)n * 2 * sizeof(float), stream);
        fb_deg_kernel<<<4096, BLK, 0, stream>>>(dst, E, deg);
        fb_np_kernel<<<node_blocks, BLK, 0, stream>>>(x, W, deg, n, dinv, hs);
        fb_scatter_kernel<<<4096, BLK, 0, stream>>>(src, dst, E, hs, s);
        fb_finalize_kernel<<<node_blocks, BLK, 0, stream>>>(x, s, hs, dinv, b, (float*)d_out, n);
    }
}

// Round 7
// 240.688 us; speedup vs baseline: 1.8116x; 1.5282x over previous
//
#include <hip/hip_runtime.h>
#include <hip/hip_fp16.h>

constexpr float ACCEL_SCALE = 0.01f;
constexpr float MAX_VEL = 0.1f;
constexpr float MAX_POS = 1.0f;

constexpr int GSHIFT = 11;            // 2048 nodes per group
constexpr int GSIZE  = 1 << GSHIFT;
constexpr int SCANW  = 128;           // requires NG+1 <= SCANW
constexpr int ANBLK  = 512;           // slices in pass 1
constexpr int DSHIFT = 4;             // deg split 16
constexpr int ASHIFT = 5;             // acc split 32

// ---- pass 1: block-local sort by dst-group; packed = (src<<11)|local_dst ----
__global__ __launch_bounds__(256) void a_scatter_kernel(
    const int* __restrict__ src, const int* __restrict__ dst,
    int E, int NG, int chunk,
    unsigned* __restrict__ tab, unsigned* __restrict__ packed)
{
    __shared__ int cnt[SCANW];
    __shared__ int tmp[SCANW];
    __shared__ int cur[SCANW];
    int tid = threadIdx.x;
    long long cs64 = (long long)blockIdx.x * chunk;
    int cs = (cs64 > E) ? E : (int)cs64;
    int ce = min(cs + chunk, E);

    if (tid < SCANW) cnt[tid] = 0;
    __syncthreads();

    int nv = (ce - cs) >> 2;
    const int4* d4 = (const int4*)(dst + cs);
    for (int k = tid; k < nv; k += 256) {
        int4 v = d4[k];
        atomicAdd(&cnt[v.x >> GSHIFT], 1);
        atomicAdd(&cnt[v.y >> GSHIFT], 1);
        atomicAdd(&cnt[v.z >> GSHIFT], 1);
        atomicAdd(&cnt[v.w >> GSHIFT], 1);
    }
    for (int i = cs + (nv << 2) + tid; i < ce; i += 256)
        atomicAdd(&cnt[dst[i] >> GSHIFT], 1);
    __syncthreads();

    int v = (tid < SCANW) ? cnt[tid] : 0;
    if (tid < SCANW) tmp[tid] = v;
    __syncthreads();
    for (int off = 1; off < SCANW; off <<= 1) {
        int t = (tid < SCANW && tid >= off) ? tmp[tid - off] : 0;
        __syncthreads();
        if (tid < SCANW) tmp[tid] += t;
        __syncthreads();
    }
    if (tid < SCANW) {
        int base = tmp[tid] - v;
        cur[tid] = base;
        if (tid <= NG) tab[(size_t)blockIdx.x * (NG + 1) + tid] = (unsigned)base;
    }
    __syncthreads();

    const int4* s4 = (const int4*)(src + cs);
    for (int k = tid; k < nv; k += 256) {
        int4 dv = d4[k];
        int4 sv = s4[k];
        int p;
        p = atomicAdd(&cur[dv.x >> GSHIFT], 1);
        packed[cs + p] = ((unsigned)sv.x << GSHIFT) | (unsigned)(dv.x & (GSIZE - 1));
        p = atomicAdd(&cur[dv.y >> GSHIFT], 1);
        packed[cs + p] = ((unsigned)sv.y << GSHIFT) | (unsigned)(dv.y & (GSIZE - 1));
        p = atomicAdd(&cur[dv.z >> GSHIFT], 1);
        packed[cs + p] = ((unsigned)sv.z << GSHIFT) | (unsigned)(dv.z & (GSIZE - 1));
        p = atomicAdd(&cur[dv.w >> GSHIFT], 1);
        packed[cs + p] = ((unsigned)sv.w << GSHIFT) | (unsigned)(dv.w & (GSIZE - 1));
    }
    for (int i = cs + (nv << 2) + tid; i < ce; i += 256) {
        int dvv = dst[i], svv = src[i];
        int p = atomicAdd(&cur[dvv >> GSHIFT], 1);
        packed[cs + p] = ((unsigned)svv << GSHIFT) | (unsigned)(dvv & (GSIZE - 1));
    }
}

// ---- pass 2: per-(group,split) degree count via LDS counters -> pdeg partials ----
__global__ __launch_bounds__(512) void f_deg_kernel(
    const unsigned* __restrict__ packed, const unsigned* __restrict__ tab,
    int E, int NG, int chunk, int n, int splitShift, int* __restrict__ pdeg)
{
    __shared__ int cnt[GSIZE];
    int g = blockIdx.x >> splitShift;
    int s = blockIdx.x & ((1 << splitShift) - 1);
    for (int t = threadIdx.x; t < GSIZE; t += 512) cnt[t] = 0;
    __syncthreads();
    int wave = threadIdx.x >> 6, lane = threadIdx.x & 63;
    int perSplit = ANBLK >> splitShift;
    int j0 = s * perSplit, jend = j0 + perSplit;
    int j = j0 + wave;
    unsigned nt0 = 0, nt1 = 0;
    if (j < jend) { const unsigned* tr = tab + (size_t)j * (NG + 1) + g; nt0 = tr[0]; nt1 = tr[1]; }
    for (; j < jend; j += 8) {
        unsigned t0 = nt0, t1 = nt1;
        int jn = j + 8;
        if (jn < jend) { const unsigned* tr = tab + (size_t)jn * (NG + 1) + g; nt0 = tr[0]; nt1 = tr[1]; }
        long long cs64 = (long long)j * chunk;
        int cs = (cs64 > E) ? E : (int)cs64;
        for (unsigned i = t0 + lane; i < t1; i += 64)
            atomicAdd(&cnt[packed[cs + i] & (GSIZE - 1)], 1);
    }
    __syncthreads();
    size_t nb0 = (size_t)g << GSHIFT;
    for (int t = threadIdx.x; t < GSIZE; t += 512) {
        size_t node = nb0 + t;
        if (node < (size_t)n) pdeg[(size_t)s * n + node] = cnt[t];
    }
}

// ---- fused: dinv = rsqrt(1 + sum pdeg); hsh = half2((x@W) * dinv) ----
__global__ void node_preh_kernel(const float* __restrict__ x, const float* __restrict__ W,
                                 const int* __restrict__ pdeg, int n, int nsplit,
                                 float* __restrict__ dinv, __half2* __restrict__ hsh) {
    int i = blockIdx.x * blockDim.x + threadIdx.x;
    if (i >= n) return;
    int d = 1;   // self loop
    for (int s = 0; s < nsplit; ++s) d += pdeg[(size_t)s * n + i];
    float di = rsqrtf((float)d);
    dinv[i] = di;
    const float* xr = x + (size_t)i * 5;
    float x0 = xr[0], x1 = xr[1], x2 = xr[2], x3 = xr[3], x4 = xr[4];
    float h0 = x0 * W[0] + x1 * W[2] + x2 * W[4] + x3 * W[6] + x4 * W[8];
    float h1 = x0 * W[1] + x1 * W[3] + x2 * W[5] + x3 * W[7] + x4 * W[9];
    hsh[i] = __floats2half2_rn(h0 * di, h1 * di);
}

// ---- pass 3: per-(group,split) accumulate; split 32 for CU balance ----
__global__ __launch_bounds__(512) void a_acc4_kernel(
    const unsigned* __restrict__ packed, const unsigned* __restrict__ tab,
    const __half2* __restrict__ hsh, int E, int NG, int chunk, int n,
    __half2* __restrict__ psh)
{
    __shared__ float accx[GSIZE];
    __shared__ float accy[GSIZE];
    int g = blockIdx.x >> ASHIFT;
    int s = blockIdx.x & ((1 << ASHIFT) - 1);
    for (int t = threadIdx.x; t < GSIZE; t += 512) { accx[t] = 0.f; accy[t] = 0.f; }
    __syncthreads();
    int wave = threadIdx.x >> 6, lane = threadIdx.x & 63;
    const int perSplit = ANBLK >> ASHIFT;     // 16 slices
    int j0 = s * perSplit, jend = j0 + perSplit;
    int j = j0 + wave;
    unsigned nt0 = 0, nt1 = 0;
    if (j < jend) { const unsigned* tr = tab + (size_t)j * (NG + 1) + g; nt0 = tr[0]; nt1 = tr[1]; }
    for (; j < jend; j += 8) {
        unsigned t0 = nt0, t1 = nt1;
        int jn = j + 8;
        if (jn < jend) { const unsigned* tr = tab + (size_t)jn * (NG + 1) + g; nt0 = tr[0]; nt1 = tr[1]; }
        long long cs64 = (long long)j * chunk;
        int cs = (cs64 > E) ? E : (int)cs64;
        for (unsigned i = t0 + lane; i < t1; i += 64) {
            unsigned p = packed[cs + i];
            float2 m = __half22float2(hsh[p >> GSHIFT]);
            int ld = p & (GSIZE - 1);
            unsafeAtomicAdd(&accx[ld], m.x);
            unsafeAtomicAdd(&accy[ld], m.y);
        }
    }
    __syncthreads();
    size_t nb0 = (size_t)g << GSHIFT;
    for (int t = threadIdx.x; t < GSIZE; t += 512) {
        size_t node = nb0 + t;
        if (node < (size_t)n)
            psh[(size_t)s * n + node] = __floats2half2_rn(accx[t], accy[t]);
    }
}

// ---- final: sum 32 half2 partials, recompute self term in f32, integrate ----
__global__ void a_finalh_kernel(const float* __restrict__ x, const __half2* __restrict__ psh,
                                const float* __restrict__ W, const float* __restrict__ dinv,
                                const float* __restrict__ b, float* __restrict__ out,
                                int n, int nsplit) {
    int i = blockIdx.x * blockDim.x + threadIdx.x;
    if (i >= n) return;
    float sx = 0.f, sy = 0.f;
    for (int s = 0; s < nsplit; ++s) {
        float2 v = __half22float2(psh[(size_t)s * n + i]);
        sx += v.x; sy += v.y;
    }
    float di = dinv[i];
    const float* xr = x + (size_t)i * 5;
    float x0 = xr[0], x1 = xr[1], x2 = xr[2], x3 = xr[3], x4 = xr[4];
    float h0 = x0 * W[0] + x1 * W[2] + x2 * W[4] + x3 * W[6] + x4 * W[8];
    float h1 = x0 * W[1] + x1 * W[3] + x2 * W[5] + x3 * W[7] + x4 * W[9];
    float c0 = di * (sx + h0 * di) + b[0];
    float c1 = di * (sy + h1 * di) + b[1];
    float a0 = c0 * ACCEL_SCALE;
    float a1 = c1 * ACCEL_SCALE;
    float v0 = fminf(fmaxf(x2 + a0, -MAX_VEL), MAX_VEL);
    float v1 = fminf(fmaxf(x3 + a1, -MAX_VEL), MAX_VEL);
    float p0 = fminf(fmaxf(x0 + v0, -MAX_POS), MAX_POS);
    float p1 = fminf(fmaxf(x1 + v1, -MAX_POS), MAX_POS);
    float* o = out + (size_t)i * 5;
    o[0] = p0; o[1] = p1; o[2] = v0; o[3] = v1; o[4] = x4;
}

// ============================ PATH F: round-4 fallback (f32, split 4) ============================
__global__ void node_pre_kernel(const float* __restrict__ x, const float* __restrict__ W,
                                const int* __restrict__ pdeg, int n, int nsplit,
                                float* __restrict__ dinv, float* __restrict__ hs) {
    int i = blockIdx.x * blockDim.x + threadIdx.x;
    if (i >= n) return;
    int d = 1;
    for (int s = 0; s < nsplit; ++s) d += pdeg[(size_t)s * n + i];
    float di = rsqrtf((float)d);
    dinv[i] = di;
    const float* xr = x + (size_t)i * 5;
    float x0 = xr[0], x1 = xr[1], x2 = xr[2], x3 = xr[3], x4 = xr[4];
    float h0 = x0 * W[0] + x1 * W[2] + x2 * W[4] + x3 * W[6] + x4 * W[8];
    float h1 = x0 * W[1] + x1 * W[3] + x2 * W[5] + x3 * W[7] + x4 * W[9];
    hs[2 * i]     = h0 * di;
    hs[2 * i + 1] = h1 * di;
}

__global__ __launch_bounds__(512) void f_acc_kernel(
    const unsigned* __restrict__ packed, const unsigned* __restrict__ tab,
    const float* __restrict__ hs, int E, int NG, int chunk, int n, int splitShift,
    float2* __restrict__ ps)
{
    __shared__ float accx[GSIZE];
    __shared__ float accy[GSIZE];
    int g = blockIdx.x >> splitShift;
    int s = blockIdx.x & ((1 << splitShift) - 1);
    for (int t = threadIdx.x; t < GSIZE; t += 512) { accx[t] = 0.f; accy[t] = 0.f; }
    __syncthreads();
    int wave = threadIdx.x >> 6, lane = threadIdx.x & 63;
    int perSplit = ANBLK >> splitShift;
    int j0 = s * perSplit, jend = j0 + perSplit;
    const float2* h2 = (const float2*)hs;
    int j = j0 + wave;
    unsigned nt0 = 0, nt1 = 0;
    if (j < jend) { const unsigned* tr = tab + (size_t)j * (NG + 1) + g; nt0 = tr[0]; nt1 = tr[1]; }
    for (; j < jend; j += 8) {
        unsigned t0 = nt0, t1 = nt1;
        int jn = j + 8;
        if (jn < jend) { const unsigned* tr = tab + (size_t)jn * (NG + 1) + g; nt0 = tr[0]; nt1 = tr[1]; }
        long long cs64 = (long long)j * chunk;
        int cs = (cs64 > E) ? E : (int)cs64;
        for (unsigned i = t0 + lane; i < t1; i += 64) {
            unsigned p = packed[cs + i];
            float2 m = h2[p >> GSHIFT];
            int ld = p & (GSIZE - 1);
            unsafeAtomicAdd(&accx[ld], m.x);
            unsafeAtomicAdd(&accy[ld], m.y);
        }
    }
    __syncthreads();
    size_t nb0 = (size_t)g << GSHIFT;
    for (int t = threadIdx.x; t < GSIZE; t += 512) {
        size_t node = nb0 + t;
        if (node < (size_t)n) ps[(size_t)s * n + node] = make_float2(accx[t], accy[t]);
    }
}

__global__ void a_final_kernel(const float* __restrict__ x, const float2* __restrict__ ps,
                               const float* __restrict__ hs, const float* __restrict__ dinv,
                               const float* __restrict__ b, float* __restrict__ out,
                               int n, int nsplit) {
    int i = blockIdx.x * blockDim.x + threadIdx.x;
    if (i >= n) return;
    float sx = 0.f, sy = 0.f;
    for (int s = 0; s < nsplit; ++s) {
        float2 v = ps[(size_t)s * n + i];
        sx += v.x; sy += v.y;
    }
    const float2* h2 = (const float2*)hs;
    float di = dinv[i];
    float2 hv = h2[i];
    float c0 = di * (sx + hv.x) + b[0];
    float c1 = di * (sy + hv.y) + b[1];
    float a0 = c0 * ACCEL_SCALE;
    float a1 = c1 * ACCEL_SCALE;
    const float* xr = x + (size_t)i * 5;
    float v0 = fminf(fmaxf(xr[2] + a0, -MAX_VEL), MAX_VEL);
    float v1 = fminf(fmaxf(xr[3] + a1, -MAX_VEL), MAX_VEL);
    float p0 = fminf(fmaxf(xr[0] + v0, -MAX_POS), MAX_POS);
    float p1 = fminf(fmaxf(xr[1] + v1, -MAX_POS), MAX_POS);
    float* o = out + (size_t)i * 5;
    o[0] = p0; o[1] = p1; o[2] = v0; o[3] = v1; o[4] = xr[4];
}

// ============================ PATH C: atomic fallback ============================
__global__ void fb_deg_kernel(const int* __restrict__ dst, int E, int* __restrict__ deg) {
    int tid = blockIdx.x * blockDim.x + threadIdx.x;
    int stride = gridDim.x * blockDim.x;
    for (int k = tid; k < E; k += stride) atomicAdd(&deg[dst[k]], 1);
}
__global__ void fb_scatter_kernel(const int* __restrict__ src, const int* __restrict__ dst,
                                  int E, const float* __restrict__ hs, float* __restrict__ s) {
    int tid = blockIdx.x * blockDim.x + threadIdx.x;
    int stride = gridDim.x * blockDim.x;
    const float2* h2 = (const float2*)hs;
    for (int k = tid; k < E; k += stride) {
        int sv = src[k], dv = dst[k];
        float2 m = h2[sv];
        unsafeAtomicAdd(&s[2 * dv], m.x);
        unsafeAtomicAdd(&s[2 * dv + 1], m.y);
    }
}
__global__ void fb_np_kernel(const float* __restrict__ x, const float* __restrict__ W,
                             const int* __restrict__ deg, int n,
                             float* __restrict__ dinv, float* __restrict__ hs) {
    int i = blockIdx.x * blockDim.x + threadIdx.x;
    if (i >= n) return;
    float di = rsqrtf((float)(deg[i] + 1));
    dinv[i] = di;
    const float* xr = x + (size_t)i * 5;
    float x0 = xr[0], x1 = xr[1], x2 = xr[2], x3 = xr[3], x4 = xr[4];
    float h0 = x0 * W[0] + x1 * W[2] + x2 * W[4] + x3 * W[6] + x4 * W[8];
    float h1 = x0 * W[1] + x1 * W[3] + x2 * W[5] + x3 * W[7] + x4 * W[9];
    hs[2 * i] = h0 * di;
    hs[2 * i + 1] = h1 * di;
}
__global__ void fb_finalize_kernel(const float* __restrict__ x, const float* __restrict__ s,
                                   const float* __restrict__ hs, const float* __restrict__ dinv,
                                   const float* __restrict__ b, float* __restrict__ out, int n) {
    int i = blockIdx.x * blockDim.x + threadIdx.x;
    if (i >= n) return;
    float di = dinv[i];
    const float2* s2 = (const float2*)s;
    const float2* h2 = (const float2*)hs;
    float2 sv = s2[i];
    float2 hv = h2[i];
    float c0 = di * (sv.x + hv.x) + b[0];
    float c1 = di * (sv.y + hv.y) + b[1];
    float a0 = c0 * ACCEL_SCALE, a1 = c1 * ACCEL_SCALE;
    const float* xr = x + (size_t)i * 5;
    float v0 = fminf(fmaxf(xr[2] + a0, -MAX_VEL), MAX_VEL);
    float v1 = fminf(fmaxf(xr[3] + a1, -MAX_VEL), MAX_VEL);
    float p0 = fminf(fmaxf(xr[0] + v0, -MAX_POS), MAX_POS);
    float p1 = fminf(fmaxf(xr[1] + v1, -MAX_POS), MAX_POS);
    float* o = out + (size_t)i * 5;
    o[0] = p0; o[1] = p1; o[2] = v0; o[3] = v1; o[4] = xr[4];
}

extern "C" void kernel_launch(void* const* d_in, const int* in_sizes, int n_in,
                              void* d_out, int out_size, void* d_ws, size_t ws_size,
                              hipStream_t stream) {
    const float* x    = (const float*)d_in[0];
    const int*   edge = (const int*)d_in[1];
    const float* W    = (const float*)d_in[2];
    const float* b    = (const float*)d_in[3];

    int n = in_sizes[0] / 5;
    int E = in_sizes[1] / 2;
    const int* src = edge;
    const int* dst = edge + E;

    const int BLK = 256;
    int node_blocks = (n + BLK - 1) / BLK;
    int NG = (n + GSIZE - 1) >> GSHIFT;
    int chunk = ((E + ANBLK - 1) / ANBLK + 3) & ~3;
    bool geomOK = (NG >= 1) && (NG + 1 <= SCANW) && (n <= (1 << 21)) && (E >= 8);

    // ---------- path A (v7): scatter -> deg(split16) -> node_pre(half2) -> acc(split32) ----------
    if (geomOK) {
        const int dsplit = 1 << DSHIFT;      // 16
        const int asplit = 1 << ASHIFT;      // 32
        size_t wTab = (size_t)ANBLK * (NG + 1);
        // words: packed E | tab | pdeg 16n | psh 32n(half2=1 word) | dinv n | hsh n
        size_t needW = (size_t)E + wTab + (size_t)dsplit * n + (size_t)asplit * n
                     + (size_t)n + (size_t)n;
        if (ws_size >= needW * 4) {
            unsigned* packed = (unsigned*)d_ws;
            unsigned* tab    = packed + E;
            int*      pdeg   = (int*)(tab + wTab);
            __half2*  psh    = (__half2*)(pdeg + (size_t)dsplit * n);
            float*    dinv   = (float*)(psh + (size_t)asplit * n);
            __half2*  hsh    = (__half2*)(dinv + n);

            a_scatter_kernel<<<ANBLK, 256, 0, stream>>>(src, dst, E, NG, chunk, tab, packed);
            f_deg_kernel<<<NG << DSHIFT, 512, 0, stream>>>(packed, tab, E, NG, chunk, n,
                                                           DSHIFT, pdeg);
            node_preh_kernel<<<node_blocks, BLK, 0, stream>>>(x, W, pdeg, n, dsplit, dinv, hsh);
            a_acc4_kernel<<<NG << ASHIFT, 512, 0, stream>>>(packed, tab, hsh, E, NG, chunk, n,
                                                            psh);
            a_finalh_kernel<<<node_blocks, BLK, 0, stream>>>(x, psh, W, dinv, b,
                                                             (float*)d_out, n, asplit);
            return;
        }
    }

    // ---------- path F: round-4 pipeline (f32, split 4) ----------
    if (geomOK) {
        size_t baseW = (size_t)E + (size_t)ANBLK * (NG + 1) + (size_t)n + 2 * (size_t)n;
        size_t needF = (baseW + (size_t)4 * n * 2) * 4;
        if (ws_size >= needF) {
            const int splitShift = 2, split = 4;
            unsigned* packed = (unsigned*)d_ws;
            unsigned* tab    = packed + E;
            int* region      = (int*)(tab + (size_t)ANBLK * (NG + 1));
            int* pdeg        = region;
            float2* ps       = (float2*)region;
            float* dinv      = (float*)(region + (size_t)split * n * 2);
            float* hs        = dinv + n;

            a_scatter_kernel<<<ANBLK, 256, 0, stream>>>(src, dst, E, NG, chunk, tab, packed);
            f_deg_kernel<<<NG << splitShift, 512, 0, stream>>>(packed, tab, E, NG, chunk, n,
                                                               splitShift, pdeg);
            node_pre_kernel<<<node_blocks, BLK, 0, stream>>>(x, W, pdeg, n, split, dinv, hs);
            f_acc_kernel<<<NG << splitShift, 512, 0, stream>>>(packed, tab, hs, E, NG, chunk, n,
                                                               splitShift, ps);
            a_final_kernel<<<node_blocks, BLK, 0, stream>>>(x, ps, hs, dinv, b,
                                                            (float*)d_out, n, split);
            return;
        }
    }

    // ---------- path C: atomic fallback ----------
    {
        float* dinv = (float*)d_ws;
        float* hs   = dinv + n;
        float* s    = hs + 2 * (size_t)n;
        int*   deg  = (int*)(s + 2 * (size_t)n);
        hipMemsetAsync(deg, 0, (size_t)n * sizeof(int), stream);
        hipMemsetAsync(s,   0, (size_t)n * 2 * sizeof(float), stream);
        fb_deg_kernel<<<4096, BLK, 0, stream>>>(dst, E, deg);
        fb_np_kernel<<<node_blocks, BLK, 0, stream>>>(x, W, deg, n, dinv, hs);
        fb_scatter_kernel<<<4096, BLK, 0, stream>>>(src, dst, E, hs, s);
        fb_finalize_kernel<<<node_blocks, BLK, 0, stream>>>(x, s, hs, dinv, b, (float*)d_out, n);
    }
}

// Round 8
// 173.480 us; speedup vs baseline: 2.5134x; 1.3874x over previous
//
#include <hip/hip_runtime.h>
#include <hip/hip_fp16.h>

constexpr float ACCEL_SCALE = 0.01f;
constexpr float MAX_VEL = 0.1f;
constexpr float MAX_POS = 1.0f;

constexpr int GSHIFT = 11;            // 2048 nodes per group
constexpr int GSIZE  = 1 << GSHIFT;
constexpr int SCANW  = 128;           // requires NG+1 <= SCANW
constexpr int ANBLK  = 512;           // slices in pass 1
constexpr int DSHIFT = 4;             // deg split 16
constexpr int ASHIFT = 5;             // acc split 32

// ---- pass 1: block-local sort by dst-group; packed = (src<<11)|local_dst ----
__global__ __launch_bounds__(256) void a_scatter_kernel(
    const int* __restrict__ src, const int* __restrict__ dst,
    int E, int NG, int chunk,
    unsigned* __restrict__ tab, unsigned* __restrict__ packed)
{
    __shared__ int cnt[SCANW];
    __shared__ int tmp[SCANW];
    __shared__ int cur[SCANW];
    int tid = threadIdx.x;
    long long cs64 = (long long)blockIdx.x * chunk;
    int cs = (cs64 > E) ? E : (int)cs64;
    int ce = min(cs + chunk, E);

    if (tid < SCANW) cnt[tid] = 0;
    __syncthreads();

    int nv = (ce - cs) >> 2;
    const int4* d4 = (const int4*)(dst + cs);
    for (int k = tid; k < nv; k += 256) {
        int4 v = d4[k];
        atomicAdd(&cnt[v.x >> GSHIFT], 1);
        atomicAdd(&cnt[v.y >> GSHIFT], 1);
        atomicAdd(&cnt[v.z >> GSHIFT], 1);
        atomicAdd(&cnt[v.w >> GSHIFT], 1);
    }
    for (int i = cs + (nv << 2) + tid; i < ce; i += 256)
        atomicAdd(&cnt[dst[i] >> GSHIFT], 1);
    __syncthreads();

    int v = (tid < SCANW) ? cnt[tid] : 0;
    if (tid < SCANW) tmp[tid] = v;
    __syncthreads();
    for (int off = 1; off < SCANW; off <<= 1) {
        int t = (tid < SCANW && tid >= off) ? tmp[tid - off] : 0;
        __syncthreads();
        if (tid < SCANW) tmp[tid] += t;
        __syncthreads();
    }
    if (tid < SCANW) {
        int base = tmp[tid] - v;
        cur[tid] = base;
        if (tid <= NG) tab[(size_t)blockIdx.x * (NG + 1) + tid] = (unsigned)base;
    }
    __syncthreads();

    const int4* s4 = (const int4*)(src + cs);
    for (int k = tid; k < nv; k += 256) {
        int4 dv = d4[k];
        int4 sv = s4[k];
        int p;
        p = atomicAdd(&cur[dv.x >> GSHIFT], 1);
        packed[cs + p] = ((unsigned)sv.x << GSHIFT) | (unsigned)(dv.x & (GSIZE - 1));
        p = atomicAdd(&cur[dv.y >> GSHIFT], 1);
        packed[cs + p] = ((unsigned)sv.y << GSHIFT) | (unsigned)(dv.y & (GSIZE - 1));
        p = atomicAdd(&cur[dv.z >> GSHIFT], 1);
        packed[cs + p] = ((unsigned)sv.z << GSHIFT) | (unsigned)(dv.z & (GSIZE - 1));
        p = atomicAdd(&cur[dv.w >> GSHIFT], 1);
        packed[cs + p] = ((unsigned)sv.w << GSHIFT) | (unsigned)(dv.w & (GSIZE - 1));
    }
    for (int i = cs + (nv << 2) + tid; i < ce; i += 256) {
        int dvv = dst[i], svv = src[i];
        int p = atomicAdd(&cur[dvv >> GSHIFT], 1);
        packed[cs + p] = ((unsigned)svv << GSHIFT) | (unsigned)(dvv & (GSIZE - 1));
    }
}

// ---- pass 2: per-(group,split) degree count via LDS counters -> pdeg partials ----
__global__ __launch_bounds__(512) void f_deg_kernel(
    const unsigned* __restrict__ packed, const unsigned* __restrict__ tab,
    int E, int NG, int chunk, int n, int splitShift, int* __restrict__ pdeg)
{
    __shared__ int cnt[GSIZE];
    int g = blockIdx.x >> splitShift;
    int s = blockIdx.x & ((1 << splitShift) - 1);
    for (int t = threadIdx.x; t < GSIZE; t += 512) cnt[t] = 0;
    __syncthreads();
    int wave = threadIdx.x >> 6, lane = threadIdx.x & 63;
    int perSplit = ANBLK >> splitShift;
    int j0 = s * perSplit, jend = j0 + perSplit;
    int j = j0 + wave;
    unsigned nt0 = 0, nt1 = 0;
    if (j < jend) { const unsigned* tr = tab + (size_t)j * (NG + 1) + g; nt0 = tr[0]; nt1 = tr[1]; }
    for (; j < jend; j += 8) {
        unsigned t0 = nt0, t1 = nt1;
        int jn = j + 8;
        if (jn < jend) { const unsigned* tr = tab + (size_t)jn * (NG + 1) + g; nt0 = tr[0]; nt1 = tr[1]; }
        long long cs64 = (long long)j * chunk;
        int cs = (cs64 > E) ? E : (int)cs64;
        for (unsigned i = t0 + lane; i < t1; i += 64)
            atomicAdd(&cnt[packed[cs + i] & (GSIZE - 1)], 1);
    }
    __syncthreads();
    size_t nb0 = (size_t)g << GSHIFT;
    for (int t = threadIdx.x; t < GSIZE; t += 512) {
        size_t node = nb0 + t;
        if (node < (size_t)n) pdeg[(size_t)s * n + node] = cnt[t];
    }
}

// ---- fused: dinv = rsqrt(1 + sum pdeg); hsh = half2((x@W) * dinv) ----
__global__ void node_preh_kernel(const float* __restrict__ x, const float* __restrict__ W,
                                 const int* __restrict__ pdeg, int n, int nsplit,
                                 float* __restrict__ dinv, __half2* __restrict__ hsh) {
    int i = blockIdx.x * blockDim.x + threadIdx.x;
    if (i >= n) return;
    int d = 1;   // self loop
    for (int s = 0; s < nsplit; ++s) d += pdeg[(size_t)s * n + i];
    float di = rsqrtf((float)d);
    dinv[i] = di;
    const float* xr = x + (size_t)i * 5;
    float x0 = xr[0], x1 = xr[1], x2 = xr[2], x3 = xr[3], x4 = xr[4];
    float h0 = x0 * W[0] + x1 * W[2] + x2 * W[4] + x3 * W[6] + x4 * W[8];
    float h1 = x0 * W[1] + x1 * W[3] + x2 * W[5] + x3 * W[7] + x4 * W[9];
    hsh[i] = __floats2half2_rn(h0 * di, h1 * di);
}

// ---- pass 3: per-(group,split) accumulate with packed half2 LDS atomics ----
__global__ __launch_bounds__(512) void a_acc5_kernel(
    const unsigned* __restrict__ packed, const unsigned* __restrict__ tab,
    const __half2* __restrict__ hsh, int E, int NG, int chunk, int n,
    __half2* __restrict__ psh)
{
    __shared__ __half2 acc[GSIZE];     // 8 KB
    int g = blockIdx.x >> ASHIFT;
    int s = blockIdx.x & ((1 << ASHIFT) - 1);
    const __half2 zero = __floats2half2_rn(0.f, 0.f);
    for (int t = threadIdx.x; t < GSIZE; t += 512) acc[t] = zero;
    __syncthreads();
    int wave = threadIdx.x >> 6, lane = threadIdx.x & 63;
    const int perSplit = ANBLK >> ASHIFT;     // 16 slices
    int j0 = s * perSplit, jend = j0 + perSplit;
    int j = j0 + wave;
    unsigned nt0 = 0, nt1 = 0;
    if (j < jend) { const unsigned* tr = tab + (size_t)j * (NG + 1) + g; nt0 = tr[0]; nt1 = tr[1]; }
    for (; j < jend; j += 8) {
        unsigned t0 = nt0, t1 = nt1;
        int jn = j + 8;
        if (jn < jend) { const unsigned* tr = tab + (size_t)jn * (NG + 1) + g; nt0 = tr[0]; nt1 = tr[1]; }
        long long cs64 = (long long)j * chunk;
        int cs = (cs64 > E) ? E : (int)cs64;
        for (unsigned i = t0 + lane; i < t1; i += 64) {
            unsigned p = packed[cs + i];
            __half2 m = hsh[p >> GSHIFT];
            unsafeAtomicAdd(&acc[p & (GSIZE - 1)], m);
        }
    }
    __syncthreads();
    size_t nb0 = (size_t)g << GSHIFT;
    for (int t = threadIdx.x; t < GSIZE; t += 512) {
        size_t node = nb0 + t;
        if (node < (size_t)n) psh[(size_t)s * n + node] = acc[t];
    }
}

// ---- final: sum 32 half2 partials in f32, recompute self term, integrate ----
__global__ void a_finalh_kernel(const float* __restrict__ x, const __half2* __restrict__ psh,
                                const float* __restrict__ W, const float* __restrict__ dinv,
                                const float* __restrict__ b, float* __restrict__ out,
                                int n, int nsplit) {
    int i = blockIdx.x * blockDim.x + threadIdx.x;
    if (i >= n) return;
    float sx = 0.f, sy = 0.f;
    for (int s = 0; s < nsplit; ++s) {
        float2 v = __half22float2(psh[(size_t)s * n + i]);
        sx += v.x; sy += v.y;
    }
    float di = dinv[i];
    const float* xr = x + (size_t)i * 5;
    float x0 = xr[0], x1 = xr[1], x2 = xr[2], x3 = xr[3], x4 = xr[4];
    float h0 = x0 * W[0] + x1 * W[2] + x2 * W[4] + x3 * W[6] + x4 * W[8];
    float h1 = x0 * W[1] + x1 * W[3] + x2 * W[5] + x3 * W[7] + x4 * W[9];
    float c0 = di * (sx + h0 * di) + b[0];
    float c1 = di * (sy + h1 * di) + b[1];
    float a0 = c0 * ACCEL_SCALE;
    float a1 = c1 * ACCEL_SCALE;
    float v0 = fminf(fmaxf(x2 + a0, -MAX_VEL), MAX_VEL);
    float v1 = fminf(fmaxf(x3 + a1, -MAX_VEL), MAX_VEL);
    float p0 = fminf(fmaxf(x0 + v0, -MAX_POS), MAX_POS);
    float p1 = fminf(fmaxf(x1 + v1, -MAX_POS), MAX_POS);
    float* o = out + (size_t)i * 5;
    o[0] = p0; o[1] = p1; o[2] = v0; o[3] = v1; o[4] = x4;
}

// ============================ PATH F: f32 fallback (round-7 acc) ============================
__global__ void node_pre_kernel(const float* __restrict__ x, const float* __restrict__ W,
                                const int* __restrict__ pdeg, int n, int nsplit,
                                float* __restrict__ dinv, float* __restrict__ hs) {
    int i = blockIdx.x * blockDim.x + threadIdx.x;
    if (i >= n) return;
    int d = 1;
    for (int s = 0; s < nsplit; ++s) d += pdeg[(size_t)s * n + i];
    float di = rsqrtf((float)d);
    dinv[i] = di;
    const float* xr = x + (size_t)i * 5;
    float x0 = xr[0], x1 = xr[1], x2 = xr[2], x3 = xr[3], x4 = xr[4];
    float h0 = x0 * W[0] + x1 * W[2] + x2 * W[4] + x3 * W[6] + x4 * W[8];
    float h1 = x0 * W[1] + x1 * W[3] + x2 * W[5] + x3 * W[7] + x4 * W[9];
    hs[2 * i]     = h0 * di;
    hs[2 * i + 1] = h1 * di;
}

__global__ __launch_bounds__(512) void f_acc_kernel(
    const unsigned* __restrict__ packed, const unsigned* __restrict__ tab,
    const float* __restrict__ hs, int E, int NG, int chunk, int n, int splitShift,
    float2* __restrict__ ps)
{
    __shared__ float accx[GSIZE];
    __shared__ float accy[GSIZE];
    int g = blockIdx.x >> splitShift;
    int s = blockIdx.x & ((1 << splitShift) - 1);
    for (int t = threadIdx.x; t < GSIZE; t += 512) { accx[t] = 0.f; accy[t] = 0.f; }
    __syncthreads();
    int wave = threadIdx.x >> 6, lane = threadIdx.x & 63;
    int perSplit = ANBLK >> splitShift;
    int j0 = s * perSplit, jend = j0 + perSplit;
    const float2* h2 = (const float2*)hs;
    int j = j0 + wave;
    unsigned nt0 = 0, nt1 = 0;
    if (j < jend) { const unsigned* tr = tab + (size_t)j * (NG + 1) + g; nt0 = tr[0]; nt1 = tr[1]; }
    for (; j < jend; j += 8) {
        unsigned t0 = nt0, t1 = nt1;
        int jn = j + 8;
        if (jn < jend) { const unsigned* tr = tab + (size_t)jn * (NG + 1) + g; nt0 = tr[0]; nt1 = tr[1]; }
        long long cs64 = (long long)j * chunk;
        int cs = (cs64 > E) ? E : (int)cs64;
        for (unsigned i = t0 + lane; i < t1; i += 64) {
            unsigned p = packed[cs + i];
            float2 m = h2[p >> GSHIFT];
            int ld = p & (GSIZE - 1);
            unsafeAtomicAdd(&accx[ld], m.x);
            unsafeAtomicAdd(&accy[ld], m.y);
        }
    }
    __syncthreads();
    size_t nb0 = (size_t)g << GSHIFT;
    for (int t = threadIdx.x; t < GSIZE; t += 512) {
        size_t node = nb0 + t;
        if (node < (size_t)n) ps[(size_t)s * n + node] = make_float2(accx[t], accy[t]);
    }
}

__global__ void a_final_kernel(const float* __restrict__ x, const float2* __restrict__ ps,
                               const float* __restrict__ hs, const float* __restrict__ dinv,
                               const float* __restrict__ b, float* __restrict__ out,
                               int n, int nsplit) {
    int i = blockIdx.x * blockDim.x + threadIdx.x;
    if (i >= n) return;
    float sx = 0.f, sy = 0.f;
    for (int s = 0; s < nsplit; ++s) {
        float2 v = ps[(size_t)s * n + i];
        sx += v.x; sy += v.y;
    }
    const float2* h2 = (const float2*)hs;
    float di = dinv[i];
    float2 hv = h2[i];
    float c0 = di * (sx + hv.x) + b[0];
    float c1 = di * (sy + hv.y) + b[1];
    float a0 = c0 * ACCEL_SCALE;
    float a1 = c1 * ACCEL_SCALE;
    const float* xr = x + (size_t)i * 5;
    float v0 = fminf(fmaxf(xr[2] + a0, -MAX_VEL), MAX_VEL);
    float v1 = fminf(fmaxf(xr[3] + a1, -MAX_VEL), MAX_VEL);
    float p0 = fminf(fmaxf(xr[0] + v0, -MAX_POS), MAX_POS);
    float p1 = fminf(fmaxf(xr[1] + v1, -MAX_POS), MAX_POS);
    float* o = out + (size_t)i * 5;
    o[0] = p0; o[1] = p1; o[2] = v0; o[3] = v1; o[4] = xr[4];
}

// ============================ PATH C: atomic fallback ============================
__global__ void fb_deg_kernel(const int* __restrict__ dst, int E, int* __restrict__ deg) {
    int tid = blockIdx.x * blockDim.x + threadIdx.x;
    int stride = gridDim.x * blockDim.x;
    for (int k = tid; k < E; k += stride) atomicAdd(&deg[dst[k]], 1);
}
__global__ void fb_scatter_kernel(const int* __restrict__ src, const int* __restrict__ dst,
                                  int E, const float* __restrict__ hs, float* __restrict__ s) {
    int tid = blockIdx.x * blockDim.x + threadIdx.x;
    int stride = gridDim.x * blockDim.x;
    const float2* h2 = (const float2*)hs;
    for (int k = tid; k < E; k += stride) {
        int sv = src[k], dv = dst[k];
        float2 m = h2[sv];
        unsafeAtomicAdd(&s[2 * dv], m.x);
        unsafeAtomicAdd(&s[2 * dv + 1], m.y);
    }
}
__global__ void fb_np_kernel(const float* __restrict__ x, const float* __restrict__ W,
                             const int* __restrict__ deg, int n,
                             float* __restrict__ dinv, float* __restrict__ hs) {
    int i = blockIdx.x * blockDim.x + threadIdx.x;
    if (i >= n) return;
    float di = rsqrtf((float)(deg[i] + 1));
    dinv[i] = di;
    const float* xr = x + (size_t)i * 5;
    float x0 = xr[0], x1 = xr[1], x2 = xr[2], x3 = xr[3], x4 = xr[4];
    float h0 = x0 * W[0] + x1 * W[2] + x2 * W[4] + x3 * W[6] + x4 * W[8];
    float h1 = x0 * W[1] + x1 * W[3] + x2 * W[5] + x3 * W[7] + x4 * W[9];
    hs[2 * i] = h0 * di;
    hs[2 * i + 1] = h1 * di;
}
__global__ void fb_finalize_kernel(const float* __restrict__ x, const float* __restrict__ s,
                                   const float* __restrict__ hs, const float* __restrict__ dinv,
                                   const float* __restrict__ b, float* __restrict__ out, int n) {
    int i = blockIdx.x * blockDim.x + threadIdx.x;
    if (i >= n) return;
    float di = dinv[i];
    const float2* s2 = (const float2*)s;
    const float2* h2 = (const float2*)hs;
    float2 sv = s2[i];
    float2 hv = h2[i];
    float c0 = di * (sv.x + hv.x) + b[0];
    float c1 = di * (sv.y + hv.y) + b[1];
    float a0 = c0 * ACCEL_SCALE, a1 = c1 * ACCEL_SCALE;
    const float* xr = x + (size_t)i * 5;
    float v0 = fminf(fmaxf(xr[2] + a0, -MAX_VEL), MAX_VEL);
    float v1 = fminf(fmaxf(xr[3] + a1, -MAX_VEL), MAX_VEL);
    float p0 = fminf(fmaxf(xr[0] + v0, -MAX_POS), MAX_POS);
    float p1 = fminf(fmaxf(xr[1] + v1, -MAX_POS), MAX_POS);
    float* o = out + (size_t)i * 5;
    o[0] = p0; o[1] = p1; o[2] = v0; o[3] = v1; o[4] = xr[4];
}

extern "C" void kernel_launch(void* const* d_in, const int* in_sizes, int n_in,
                              void* d_out, int out_size, void* d_ws, size_t ws_size,
                              hipStream_t stream) {
    const float* x    = (const float*)d_in[0];
    const int*   edge = (const int*)d_in[1];
    const float* W    = (const float*)d_in[2];
    const float* b    = (const float*)d_in[3];

    int n = in_sizes[0] / 5;
    int E = in_sizes[1] / 2;
    const int* src = edge;
    const int* dst = edge + E;

    const int BLK = 256;
    int node_blocks = (n + BLK - 1) / BLK;
    int NG = (n + GSIZE - 1) >> GSHIFT;
    int chunk = ((E + ANBLK - 1) / ANBLK + 3) & ~3;
    bool geomOK = (NG >= 1) && (NG + 1 <= SCANW) && (n <= (1 << 21)) && (E >= 8);

    // ---------- path A (v8): scatter -> deg(split16) -> node_pre(half2) -> acc pk_f16(split32) ----------
    if (geomOK) {
        const int dsplit = 1 << DSHIFT;      // 16
        const int asplit = 1 << ASHIFT;      // 32
        size_t wTab = (size_t)ANBLK * (NG + 1);
        size_t needW = (size_t)E + wTab + (size_t)dsplit * n + (size_t)asplit * n
                     + (size_t)n + (size_t)n;
        if (ws_size >= needW * 4) {
            unsigned* packed = (unsigned*)d_ws;
            unsigned* tab    = packed + E;
            int*      pdeg   = (int*)(tab + wTab);
            __half2*  psh    = (__half2*)(pdeg + (size_t)dsplit * n);
            float*    dinv   = (float*)(psh + (size_t)asplit * n);
            __half2*  hsh    = (__half2*)(dinv + n);

            a_scatter_kernel<<<ANBLK, 256, 0, stream>>>(src, dst, E, NG, chunk, tab, packed);
            f_deg_kernel<<<NG << DSHIFT, 512, 0, stream>>>(packed, tab, E, NG, chunk, n,
                                                           DSHIFT, pdeg);
            node_preh_kernel<<<node_blocks, BLK, 0, stream>>>(x, W, pdeg, n, dsplit, dinv, hsh);
            a_acc5_kernel<<<NG << ASHIFT, 512, 0, stream>>>(packed, tab, hsh, E, NG, chunk, n,
                                                            psh);
            a_finalh_kernel<<<node_blocks, BLK, 0, stream>>>(x, psh, W, dinv, b,
                                                             (float*)d_out, n, asplit);
            return;
        }
    }

    // ---------- path F: f32 pipeline (split 4) ----------
    if (geomOK) {
        size_t baseW = (size_t)E + (size_t)ANBLK * (NG + 1) + (size_t)n + 2 * (size_t)n;
        size_t needF = (baseW + (size_t)4 * n * 2) * 4;
        if (ws_size >= needF) {
            const int splitShift = 2, split = 4;
            unsigned* packed = (unsigned*)d_ws;
            unsigned* tab    = packed + E;
            int* region      = (int*)(tab + (size_t)ANBLK * (NG + 1));
            int* pdeg        = region;
            float2* ps       = (float2*)region;
            float* dinv      = (float*)(region + (size_t)split * n * 2);
            float* hs        = dinv + n;

            a_scatter_kernel<<<ANBLK, 256, 0, stream>>>(src, dst, E, NG, chunk, tab, packed);
            f_deg_kernel<<<NG << splitShift, 512, 0, stream>>>(packed, tab, E, NG, chunk, n,
                                                               splitShift, pdeg);
            node_pre_kernel<<<node_blocks, BLK, 0, stream>>>(x, W, pdeg, n, split, dinv, hs);
            f_acc_kernel<<<NG << splitShift, 512, 0, stream>>>(packed, tab, hs, E, NG, chunk, n,
                                                               splitShift, ps);
            a_final_kernel<<<node_blocks, BLK, 0, stream>>>(x, ps, hs, dinv, b,
                                                            (float*)d_out, n, split);
            return;
        }
    }

    // ---------- path C: atomic fallback ----------
    {
        float* dinv = (float*)d_ws;
        float* hs   = dinv + n;
        float* s    = hs + 2 * (size_t)n;
        int*   deg  = (int*)(s + 2 * (size_t)n);
        hipMemsetAsync(deg, 0, (size_t)n * sizeof(int), stream);
        hipMemsetAsync(s,   0, (size_t)n * 2 * sizeof(float), stream);
        fb_deg_kernel<<<4096, BLK, 0, stream>>>(dst, E, deg);
        fb_np_kernel<<<node_blocks, BLK, 0, stream>>>(x, W, deg, n, dinv, hs);
        fb_scatter_kernel<<<4096, BLK, 0, stream>>>(src, dst, E, hs, s);
        fb_finalize_kernel<<<node_blocks, BLK, 0, stream>>>(x, s, hs, dinv, b, (float*)d_out, n);
    }
}